// Round 8
// baseline (116.176 us; speedup 1.0000x reference)
//
#include <hip/hip_runtime.h>

// EfficientPairEmbed: out[0, e, h] = sum_g emb[anum[src_e], anum[dst_e], 0, h, g] * rbf[e, g]
// rbf[e,g] = exp(-0.5/std^2 * (dist_e - offset_g)^2), offsets = linspace(0, 12, 50), std = 12/50.
//
// R7 (fixed): R6 structure (bf16 [p][g][h] table, WIN=8 windowed gather,
// 1 lane/edge) + non-temporal loads/stores for all STREAMING traffic
// (edge_index, dist, out) so the 4MB-per-XCD L2 is reserved for the one
// reusable structure: the 8MB bf16 table. nt builtins require clang native
// vector types, not HIP_vector_type structs.

#define G_NUM 50
#define H_NUM 8
#define NE_NUM 100
#define N_PAIRS (NE_NUM * NE_NUM)
#define WIN 8
#define BLOCK_THREADS 256
#define TP_PAIRS 8               // pairs per transpose block

#define SPACING (12.0f / (float)(G_NUM - 1))
#define INV_SPACING ((float)(G_NUM - 1) / 12.0f)
#define RBF_COEFF (-0.5f * ((float)G_NUM / 12.0f) * ((float)G_NUM / 12.0f))

typedef float  vfloat4 __attribute__((ext_vector_type(4)));
typedef unsigned int vuint4 __attribute__((ext_vector_type(4)));

__device__ __forceinline__ float bf_lo(unsigned u) { return __uint_as_float(u << 16); }
__device__ __forceinline__ float bf_hi(unsigned u) { return __uint_as_float(u & 0xffff0000u); }

// ---------------- Pass 0: emb [p][h][g] fp32 -> temb [p][g][h] bf16, LDS-staged ----------------
__global__ __launch_bounds__(BLOCK_THREADS) void transpose_cast_kernel(
    const float* __restrict__ emb, unsigned int* __restrict__ temb)
{
    __shared__ float ls[TP_PAIRS * H_NUM * G_NUM];          // 3200 floats, 12.8 KB

    const int tid = threadIdx.x;
    const int p0  = blockIdx.x * TP_PAIRS;

    // Coalesced read: 800 vfloat4 per block (nt: emb is read exactly once).
    const vfloat4* src = (const vfloat4*)(emb + (size_t)p0 * (H_NUM * G_NUM));
    #pragma unroll
    for (int i = tid; i < TP_PAIRS * H_NUM * G_NUM / 4; i += BLOCK_THREADS)
        ((vfloat4*)ls)[i] = __builtin_nontemporal_load(src + i);
    __syncthreads();

    // Coalesced write: 1600 packed-bf16 uints per block (cached: gather reads them next).
    unsigned int* dst = temb + (size_t)p0 * (H_NUM * G_NUM / 2);
    #pragma unroll
    for (int i = tid; i < TP_PAIRS * H_NUM * G_NUM / 2; i += BLOCK_THREADS) {
        int q  = i / (H_NUM * G_NUM / 2);          // local pair
        int u  = i - q * (H_NUM * G_NUM / 2);      // uint idx within pair: [g][h/2]
        int g  = u >> 2;
        int h0 = (u & 3) * 2;
        float f0 = ls[q * (H_NUM * G_NUM) + h0 * G_NUM + g];
        float f1 = ls[q * (H_NUM * G_NUM) + (h0 + 1) * G_NUM + g];
        unsigned u0 = __float_as_uint(f0);
        unsigned u1 = __float_as_uint(f1);
        unsigned b0 = (u0 + 0x7fffu + ((u0 >> 16) & 1u)) >> 16;   // RNE bf16
        unsigned b1 = (u1 + 0x7fffu + ((u1 >> 16) & 1u)) >> 16;
        dst[i] = (b1 << 16) | (b0 & 0xffffu);
    }
}

// ---------------- Pass 1: direct windowed gather, 1 lane/edge ----------------
__global__ __launch_bounds__(BLOCK_THREADS) void gather_kernel(
    const int* __restrict__ anum,
    const int* __restrict__ edge_index,
    const float* __restrict__ dist,
    const unsigned short* __restrict__ temb,
    float* __restrict__ out,
    int n_edges)
{
    int e = blockIdx.x * BLOCK_THREADS + threadIdx.x;
    if (e >= n_edges) return;

    // Streaming (read-once) data: non-temporal, don't allocate in L2.
    int   s  = __builtin_nontemporal_load(edge_index + e);
    int   d  = __builtin_nontemporal_load(edge_index + n_edges + e);
    float dv = __builtin_nontemporal_load(dist + e);

    int p = anum[s] * NE_NUM + anum[d];     // anum: hot 200KB, cached

    int g0 = (int)(dv * INV_SPACING) - 3;
    if (g0 < 0) g0 = 0;
    if (g0 > G_NUM - WIN) g0 = G_NUM - WIN;

    // Window rows are 16B each ([g][h0..7] bf16), 128B contiguous total. Cached.
    const unsigned short* wb = temb + (size_t)p * (H_NUM * G_NUM) + g0 * H_NUM;

    vuint4 v[WIN];
    #pragma unroll
    for (int r = 0; r < WIN; ++r)
        v[r] = *(const vuint4*)(wb + r * H_NUM);     // 8 independent 16B loads

    float a0 = 0.f, a1 = 0.f, a2 = 0.f, a3 = 0.f;
    float a4 = 0.f, a5 = 0.f, a6 = 0.f, a7 = 0.f;
    #pragma unroll
    for (int r = 0; r < WIN; ++r) {
        float diff = dv - (float)(g0 + r) * SPACING;
        float rb = __expf(RBF_COEFF * diff * diff);
        a0 += rb * bf_lo(v[r].x);
        a1 += rb * bf_hi(v[r].x);
        a2 += rb * bf_lo(v[r].y);
        a3 += rb * bf_hi(v[r].y);
        a4 += rb * bf_lo(v[r].z);
        a5 += rb * bf_hi(v[r].z);
        a6 += rb * bf_lo(v[r].w);
        a7 += rb * bf_hi(v[r].w);
    }

    // Output: write-once stream, non-temporal so it doesn't evict table lines.
    vfloat4* ob = (vfloat4*)(out + (size_t)e * H_NUM);
    vfloat4 w0 = {a0, a1, a2, a3};
    vfloat4 w1 = {a4, a5, a6, a7};
    __builtin_nontemporal_store(w0, ob);
    __builtin_nontemporal_store(w1, ob + 1);
}

// ---------------- Fallback (ws-free): exact fp32 direct kernel ----------------
__global__ __launch_bounds__(BLOCK_THREADS) void direct_kernel(
    const int* __restrict__ anum,
    const int* __restrict__ edge_index,
    const float* __restrict__ dist,
    const float* __restrict__ emb,
    float* __restrict__ out,
    int n_edges)
{
    __shared__ int   pair_s[32];
    __shared__ float dist_sd[32];
    __shared__ float rbf_sd[32 * G_NUM];

    const int tid = threadIdx.x;
    const int e0  = blockIdx.x * 32;

    if (tid < 32) {
        int e = e0 + tid;
        if (e >= n_edges) e = n_edges - 1;
        int s  = edge_index[e];
        int d  = edge_index[n_edges + e];
        pair_s[tid] = (anum[s] * NE_NUM + anum[d]) * (H_NUM * G_NUM);
        dist_sd[tid] = dist[e];
    }
    __syncthreads();

    for (int idx = tid; idx < 32 * G_NUM; idx += BLOCK_THREADS) {
        int el = idx / G_NUM;
        int g  = idx - el * G_NUM;
        float diff = dist_sd[el] - (float)g * SPACING;
        rbf_sd[idx] = __expf(RBF_COEFF * diff * diff);
    }
    __syncthreads();

    const int el = tid >> 3;
    const int h  = tid & 7;
    const float* ebase = emb + pair_s[el] + h * G_NUM;
    const float* rbase = rbf_sd + el * G_NUM;

    float acc = 0.0f;
    #pragma unroll
    for (int g2 = 0; g2 < G_NUM / 2; ++g2) {
        float2 ev = *(const float2*)(ebase + 2 * g2);
        float2 rv = *(const float2*)(rbase + 2 * g2);
        acc += ev.x * rv.x + ev.y * rv.y;
    }

    if (e0 + el < n_edges)
        out[e0 * H_NUM + tid] = acc;
}

extern "C" void kernel_launch(void* const* d_in, const int* in_sizes, int n_in,
                              void* d_out, int out_size, void* d_ws, size_t ws_size,
                              hipStream_t stream) {
    const int*   anum       = (const int*)d_in[0];
    const int*   edge_index = (const int*)d_in[1];
    const float* dist       = (const float*)d_in[2];
    const float* emb        = (const float*)d_in[3];
    float*       out        = (float*)d_out;
    const int n_edges = in_sizes[2];

    const size_t temb_bytes = (size_t)N_PAIRS * H_NUM * G_NUM * sizeof(unsigned short); // 8 MB

    if (ws_size < temb_bytes) {
        const int grid = (n_edges + 31) / 32;
        direct_kernel<<<grid, BLOCK_THREADS, 0, stream>>>(
            anum, edge_index, dist, emb, out, n_edges);
        return;
    }

    unsigned int* temb = (unsigned int*)d_ws;

    transpose_cast_kernel<<<N_PAIRS / TP_PAIRS, BLOCK_THREADS, 0, stream>>>(emb, temb);

    const int grid = (n_edges + BLOCK_THREADS - 1) / BLOCK_THREADS;
    gather_kernel<<<grid, BLOCK_THREADS, 0, stream>>>(
        anum, edge_index, dist, (const unsigned short*)temb, out, n_edges);
}

// Round 10
// 113.880 us; speedup vs baseline: 1.0202x; 1.0202x over previous
//
#include <hip/hip_runtime.h>

// EfficientPairEmbed: out[0, e, h] = sum_g emb[anum[src_e], anum[dst_e], 0, h, g] * rbf[e, g]
// rbf[e,g] = exp(-0.5/std^2 * (dist_e - offset_g)^2), offsets = linspace(0, 12, 50), std = 12/50.
//
// R8 (resubmit after infra failure): R6 structure (bf16 [p][g][h] table,
// windowed gather, 1 lane/edge), nt hints reverted (R7: neutral/negative —
// table misses are intrinsic capacity misses, not pollution). WIN 8->6:
// dropped tail terms <= 9.2e-3 relative (error budget ok vs 0.1375
// threshold), window 128->96B cuts the random-line fetch (the binding
// resource, ~3 TB/s plateau) by ~13%.

#define G_NUM 50
#define H_NUM 8
#define NE_NUM 100
#define N_PAIRS (NE_NUM * NE_NUM)
#define WIN 6
#define BLOCK_THREADS 256
#define TP_PAIRS 8               // pairs per transpose block

#define SPACING (12.0f / (float)(G_NUM - 1))
#define INV_SPACING ((float)(G_NUM - 1) / 12.0f)
#define RBF_COEFF (-0.5f * ((float)G_NUM / 12.0f) * ((float)G_NUM / 12.0f))

__device__ __forceinline__ float bf_lo(unsigned u) { return __uint_as_float(u << 16); }
__device__ __forceinline__ float bf_hi(unsigned u) { return __uint_as_float(u & 0xffff0000u); }

// ---------------- Pass 0: emb [p][h][g] fp32 -> temb [p][g][h] bf16, LDS-staged ----------------
__global__ __launch_bounds__(BLOCK_THREADS) void transpose_cast_kernel(
    const float* __restrict__ emb, unsigned int* __restrict__ temb)
{
    __shared__ float ls[TP_PAIRS * H_NUM * G_NUM];          // 3200 floats, 12.8 KB

    const int tid = threadIdx.x;
    const int p0  = blockIdx.x * TP_PAIRS;

    // Coalesced read: 800 float4 per block.
    const float4* src = (const float4*)(emb + (size_t)p0 * (H_NUM * G_NUM));
    #pragma unroll
    for (int i = tid; i < TP_PAIRS * H_NUM * G_NUM / 4; i += BLOCK_THREADS)
        ((float4*)ls)[i] = src[i];
    __syncthreads();

    // Coalesced write: 1600 packed-bf16 uints per block.
    unsigned int* dst = temb + (size_t)p0 * (H_NUM * G_NUM / 2);
    #pragma unroll
    for (int i = tid; i < TP_PAIRS * H_NUM * G_NUM / 2; i += BLOCK_THREADS) {
        int q  = i / (H_NUM * G_NUM / 2);          // local pair
        int u  = i - q * (H_NUM * G_NUM / 2);      // uint idx within pair: [g][h/2]
        int g  = u >> 2;
        int h0 = (u & 3) * 2;
        float f0 = ls[q * (H_NUM * G_NUM) + h0 * G_NUM + g];
        float f1 = ls[q * (H_NUM * G_NUM) + (h0 + 1) * G_NUM + g];
        unsigned u0 = __float_as_uint(f0);
        unsigned u1 = __float_as_uint(f1);
        unsigned b0 = (u0 + 0x7fffu + ((u0 >> 16) & 1u)) >> 16;   // RNE bf16
        unsigned b1 = (u1 + 0x7fffu + ((u1 >> 16) & 1u)) >> 16;
        dst[i] = (b1 << 16) | (b0 & 0xffffu);
    }
}

// ---------------- Pass 1: direct windowed gather, 1 lane/edge ----------------
__global__ __launch_bounds__(BLOCK_THREADS) void gather_kernel(
    const int* __restrict__ anum,
    const int* __restrict__ edge_index,
    const float* __restrict__ dist,
    const unsigned short* __restrict__ temb,
    float* __restrict__ out,
    int n_edges)
{
    int e = blockIdx.x * BLOCK_THREADS + threadIdx.x;
    if (e >= n_edges) return;

    int   s  = edge_index[e];
    int   d  = edge_index[n_edges + e];
    float dv = dist[e];

    int p = anum[s] * NE_NUM + anum[d];     // anum: hot 200KB, cached

    int g0 = (int)(dv * INV_SPACING) - 2;   // window [gc-2, gc+3]
    if (g0 < 0) g0 = 0;
    if (g0 > G_NUM - WIN) g0 = G_NUM - WIN;

    // Window rows are 16B each ([g][h0..7] bf16), 96B contiguous total.
    const unsigned short* wb = temb + (size_t)p * (H_NUM * G_NUM) + g0 * H_NUM;

    uint4 v[WIN];
    #pragma unroll
    for (int r = 0; r < WIN; ++r)
        v[r] = *(const uint4*)(wb + r * H_NUM);      // 6 independent 16B loads

    float a0 = 0.f, a1 = 0.f, a2 = 0.f, a3 = 0.f;
    float a4 = 0.f, a5 = 0.f, a6 = 0.f, a7 = 0.f;
    #pragma unroll
    for (int r = 0; r < WIN; ++r) {
        float diff = dv - (float)(g0 + r) * SPACING;
        float rb = __expf(RBF_COEFF * diff * diff);
        a0 += rb * bf_lo(v[r].x);
        a1 += rb * bf_hi(v[r].x);
        a2 += rb * bf_lo(v[r].y);
        a3 += rb * bf_hi(v[r].y);
        a4 += rb * bf_lo(v[r].z);
        a5 += rb * bf_hi(v[r].z);
        a6 += rb * bf_lo(v[r].w);
        a7 += rb * bf_hi(v[r].w);
    }

    float* ob = out + (size_t)e * H_NUM;
    *(float4*)(ob)     = make_float4(a0, a1, a2, a3);   // coalesced 32B/thread
    *(float4*)(ob + 4) = make_float4(a4, a5, a6, a7);
}

// ---------------- Fallback (ws-free): exact fp32 direct kernel ----------------
__global__ __launch_bounds__(BLOCK_THREADS) void direct_kernel(
    const int* __restrict__ anum,
    const int* __restrict__ edge_index,
    const float* __restrict__ dist,
    const float* __restrict__ emb,
    float* __restrict__ out,
    int n_edges)
{
    __shared__ int   pair_s[32];
    __shared__ float dist_sd[32];
    __shared__ float rbf_sd[32 * G_NUM];

    const int tid = threadIdx.x;
    const int e0  = blockIdx.x * 32;

    if (tid < 32) {
        int e = e0 + tid;
        if (e >= n_edges) e = n_edges - 1;
        int s  = edge_index[e];
        int d  = edge_index[n_edges + e];
        pair_s[tid] = (anum[s] * NE_NUM + anum[d]) * (H_NUM * G_NUM);
        dist_sd[tid] = dist[e];
    }
    __syncthreads();

    for (int idx = tid; idx < 32 * G_NUM; idx += BLOCK_THREADS) {
        int el = idx / G_NUM;
        int g  = idx - el * G_NUM;
        float diff = dist_sd[el] - (float)g * SPACING;
        rbf_sd[idx] = __expf(RBF_COEFF * diff * diff);
    }
    __syncthreads();

    const int el = tid >> 3;
    const int h  = tid & 7;
    const float* ebase = emb + pair_s[el] + h * G_NUM;
    const float* rbase = rbf_sd + el * G_NUM;

    float acc = 0.0f;
    #pragma unroll
    for (int g2 = 0; g2 < G_NUM / 2; ++g2) {
        float2 ev = *(const float2*)(ebase + 2 * g2);
        float2 rv = *(const float2*)(rbase + 2 * g2);
        acc += ev.x * rv.x + ev.y * rv.y;
    }

    if (e0 + el < n_edges)
        out[e0 * H_NUM + tid] = acc;
}

extern "C" void kernel_launch(void* const* d_in, const int* in_sizes, int n_in,
                              void* d_out, int out_size, void* d_ws, size_t ws_size,
                              hipStream_t stream) {
    const int*   anum       = (const int*)d_in[0];
    const int*   edge_index = (const int*)d_in[1];
    const float* dist       = (const float*)d_in[2];
    const float* emb        = (const float*)d_in[3];
    float*       out        = (float*)d_out;
    const int n_edges = in_sizes[2];

    const size_t temb_bytes = (size_t)N_PAIRS * H_NUM * G_NUM * sizeof(unsigned short); // 8 MB

    if (ws_size < temb_bytes) {
        const int grid = (n_edges + 31) / 32;
        direct_kernel<<<grid, BLOCK_THREADS, 0, stream>>>(
            anum, edge_index, dist, emb, out, n_edges);
        return;
    }

    unsigned int* temb = (unsigned int*)d_ws;

    transpose_cast_kernel<<<N_PAIRS / TP_PAIRS, BLOCK_THREADS, 0, stream>>>(emb, temb);

    const int grid = (n_edges + BLOCK_THREADS - 1) / BLOCK_THREADS;
    gather_kernel<<<grid, BLOCK_THREADS, 0, stream>>>(
        anum, edge_index, dist, (const unsigned short*)temb, out, n_edges);
}